// Round 9
// baseline (10296.789 us; speedup 1.0000x reference)
//
#include <hip/hip_runtime.h>
#include <math.h>

typedef __bf16 bf16;
typedef __attribute__((ext_vector_type(8))) __bf16 bf16x8;
typedef __attribute__((ext_vector_type(4))) float f32x4;

constexpr int TT = 32, BB = 256, HH = 384, GG = 1536;
constexpr float LN_EPS = 1e-5f;

__device__ __forceinline__ float sigm(float x) { return 1.0f / (1.0f + __expf(-x)); }

// split fp32 into 3 bf16 planes: x = h + m + l + O(2^-27 x)
__device__ __forceinline__ void split3(float x, bf16& h, bf16& m, bf16& l) {
    h = (bf16)x; float r = x - (float)h;
    m = (bf16)r; float r2 = r - (float)m;
    l = (bf16)r2;
}

// ---------------------------------------------------------------------------
// transpose + fp32 -> 3 bf16 planes, row-major permuted output (for wx):
// in[K][N] -> out[plane][n'][K], n' = ((r>>4)*4+p)*16+(r&15), n = p*384+r.
// ---------------------------------------------------------------------------
__global__ __launch_bounds__(256)
void transpose_cvt3(const float* __restrict__ in, bf16* __restrict__ out,
                    int K, int N)
{
    __shared__ float tile[32][33];
    const int k0 = blockIdx.y * 32;
    const int n0 = blockIdx.x * 32;
    const int tx = threadIdx.x & 31;
    const int ty = threadIdx.x >> 5;
    const size_t PS = (size_t)N * K;
    #pragma unroll
    for (int i = 0; i < 4; ++i)
        tile[ty + i * 8][tx] = in[(long)(k0 + ty + i * 8) * N + n0 + tx];
    __syncthreads();
    #pragma unroll
    for (int i = 0; i < 4; ++i) {
        const int n = n0 + ty + i * 8;
        const int p = n / HH, r = n - p * HH;
        const int orow = ((r >> 4) * 4 + p) * 16 + (r & 15);
        bf16 h, m, l;
        split3(tile[tx][ty + i * 8], h, m, l);
        const size_t base = (size_t)orow * K + k0 + tx;
        out[base] = h; out[PS + base] = m; out[2 * PS + base] = l;
    }
}

// ---------------------------------------------------------------------------
// transpose + split for wh -> WAVE-TILED layout (for the scan):
// out elem addr = ((pl*96 + q)*12 + ks)*512 + cc*32 + kk
// where permuted gate-row orow = q*16+cc, k = ks*32+kk.  K=384, N=1536.
// Each 1KB tile (q,ks,plane) is exactly one wave's coalesced B-fragment.
// ---------------------------------------------------------------------------
__global__ __launch_bounds__(256)
void transpose_cvt3_tiled(const float* __restrict__ in, bf16* __restrict__ out)
{
    __shared__ float tile[32][33];
    const int k0 = blockIdx.y * 32;
    const int n0 = blockIdx.x * 32;
    const int tx = threadIdx.x & 31;
    const int ty = threadIdx.x >> 5;
    constexpr size_t PS = (size_t)96 * 12 * 512;  // elems per plane
    #pragma unroll
    for (int i = 0; i < 4; ++i)
        tile[ty + i * 8][tx] = in[(long)(k0 + ty + i * 8) * GG + n0 + tx];
    __syncthreads();
    #pragma unroll
    for (int i = 0; i < 4; ++i) {
        const int n = n0 + ty + i * 8;
        const int p = n / HH, r = n - p * HH;
        const int orow = ((r >> 4) * 4 + p) * 16 + (r & 15);
        const int q = orow >> 4, cc = orow & 15;
        const int k = k0 + tx;
        const int ks = k >> 5, kk = k & 31;
        bf16 h, m, l;
        split3(tile[tx][ty + i * 8], h, m, l);
        const size_t base = ((size_t)q * 12 + ks) * 512 + cc * 32 + kk;
        out[base] = h; out[PS + base] = m; out[2 * PS + base] = l;
    }
}

// ---------------------------------------------------------------------------
// Split-precision MFMA GEMM (projections): C = A @ Bt^T. (round-7/8 verified)
// ---------------------------------------------------------------------------
template<bool CONCAT>
__global__ __launch_bounds__(256)
void gemm_proj(const float* __restrict__ A,
               const float* __restrict__ Aent, const float* __restrict__ Aspa,
               const float* __restrict__ Asca,
               const bf16* __restrict__ Bt3, float* __restrict__ C,
               int K, int N)
{
    constexpr int LDA = 40;
    __shared__ bf16 As[3][128 * LDA];
    __shared__ bf16 Bs[3][128 * LDA];
    const int tid = threadIdx.x;
    const long bm = (long)blockIdx.y * 128;
    const int bn = blockIdx.x * 128;
    const int srow = tid & 127;
    const int soff = (tid >> 7) * 16;
    const int lane = tid & 63;
    const int wid  = tid >> 6;
    const int wm = (wid >> 1) * 64, wn = (wid & 1) * 64;
    const int cc = lane & 15, g = lane >> 4;
    const size_t PS = (size_t)N * K;

    const f32x4 zero = {0.f, 0.f, 0.f, 0.f};
    f32x4 acc[4][4];
    #pragma unroll
    for (int m = 0; m < 4; ++m)
        #pragma unroll
        for (int n = 0; n < 4; ++n) acc[m][n] = zero;

    for (int k0 = 0; k0 < K; k0 += 32) {
        float va[16];
        if (!CONCAT) {
            const float* p = A + (bm + srow) * (long)K + k0 + soff;
            #pragma unroll
            for (int i = 0; i < 4; ++i) {
                const float4 v = *(const float4*)(p + i * 4);
                va[i*4+0] = v.x; va[i*4+1] = v.y; va[i*4+2] = v.z; va[i*4+3] = v.w;
            }
        } else {
            const int acol = k0 + soff;
            const float* p;
            if (acol < 256)      p = Aent + (bm + srow) * 256 + acol;
            else if (acol < 512) p = Aspa + (bm + srow) * 256 + (acol - 256);
            else                 p = Asca + (bm + srow) * 640 + (acol - 512);
            #pragma unroll
            for (int i = 0; i < 4; ++i) {
                const float4 v = *(const float4*)(p + i * 4);
                va[i*4+0] = v.x; va[i*4+1] = v.y; va[i*4+2] = v.z; va[i*4+3] = v.w;
            }
        }
        bf16 ah[16], am[16], al[16];
        #pragma unroll
        for (int e = 0; e < 16; ++e) split3(va[e], ah[e], am[e], al[e]);
        const bf16* bp = Bt3 + (bn + srow) * (long)K + k0 + soff;
        const bf16x8 b00 = *(const bf16x8*)bp;
        const bf16x8 b01 = *(const bf16x8*)(bp + 8);
        const bf16x8 b10 = *(const bf16x8*)(bp + PS);
        const bf16x8 b11 = *(const bf16x8*)(bp + PS + 8);
        const bf16x8 b20 = *(const bf16x8*)(bp + 2 * PS);
        const bf16x8 b21 = *(const bf16x8*)(bp + 2 * PS + 8);
        __syncthreads();
        *(bf16x8*)&As[0][srow * LDA + soff]     = *(bf16x8*)&ah[0];
        *(bf16x8*)&As[0][srow * LDA + soff + 8] = *(bf16x8*)&ah[8];
        *(bf16x8*)&As[1][srow * LDA + soff]     = *(bf16x8*)&am[0];
        *(bf16x8*)&As[1][srow * LDA + soff + 8] = *(bf16x8*)&am[8];
        *(bf16x8*)&As[2][srow * LDA + soff]     = *(bf16x8*)&al[0];
        *(bf16x8*)&As[2][srow * LDA + soff + 8] = *(bf16x8*)&al[8];
        *(bf16x8*)&Bs[0][srow * LDA + soff]     = b00;
        *(bf16x8*)&Bs[0][srow * LDA + soff + 8] = b01;
        *(bf16x8*)&Bs[1][srow * LDA + soff]     = b10;
        *(bf16x8*)&Bs[1][srow * LDA + soff + 8] = b11;
        *(bf16x8*)&Bs[2][srow * LDA + soff]     = b20;
        *(bf16x8*)&Bs[2][srow * LDA + soff + 8] = b21;
        __syncthreads();
        bf16x8 a0[4], a1[4], a2[4], bb[4];
        #pragma unroll
        for (int m = 0; m < 4; ++m) {
            const int off = (wm + m * 16 + cc) * LDA + g * 8;
            a0[m] = *(const bf16x8*)&As[0][off];
            a1[m] = *(const bf16x8*)&As[1][off];
            a2[m] = *(const bf16x8*)&As[2][off];
        }
        #pragma unroll
        for (int n = 0; n < 4; ++n)
            bb[n] = *(const bf16x8*)&Bs[0][(wn + n * 16 + cc) * LDA + g * 8];
        #pragma unroll
        for (int m = 0; m < 4; ++m)
            #pragma unroll
            for (int n = 0; n < 4; ++n) {
                acc[m][n] = __builtin_amdgcn_mfma_f32_16x16x32_bf16(a0[m], bb[n], acc[m][n], 0, 0, 0);
                acc[m][n] = __builtin_amdgcn_mfma_f32_16x16x32_bf16(a1[m], bb[n], acc[m][n], 0, 0, 0);
                acc[m][n] = __builtin_amdgcn_mfma_f32_16x16x32_bf16(a2[m], bb[n], acc[m][n], 0, 0, 0);
            }
        #pragma unroll
        for (int n = 0; n < 4; ++n)
            bb[n] = *(const bf16x8*)&Bs[1][(wn + n * 16 + cc) * LDA + g * 8];
        #pragma unroll
        for (int m = 0; m < 4; ++m)
            #pragma unroll
            for (int n = 0; n < 4; ++n) {
                acc[m][n] = __builtin_amdgcn_mfma_f32_16x16x32_bf16(a0[m], bb[n], acc[m][n], 0, 0, 0);
                acc[m][n] = __builtin_amdgcn_mfma_f32_16x16x32_bf16(a1[m], bb[n], acc[m][n], 0, 0, 0);
            }
        #pragma unroll
        for (int n = 0; n < 4; ++n)
            bb[n] = *(const bf16x8*)&Bs[2][(wn + n * 16 + cc) * LDA + g * 8];
        #pragma unroll
        for (int m = 0; m < 4; ++m)
            #pragma unroll
            for (int n = 0; n < 4; ++n)
                acc[m][n] = __builtin_amdgcn_mfma_f32_16x16x32_bf16(a0[m], bb[n], acc[m][n], 0, 0, 0);
    }
    #pragma unroll
    for (int m = 0; m < 4; ++m) {
        const long row0 = bm + wm + m * 16 + g * 4;
        #pragma unroll
        for (int n = 0; n < 4; ++n) {
            const int col = bn + wn + n * 16 + cc;
            #pragma unroll
            for (int r = 0; r < 4; ++r)
                C[(row0 + r) * (long)N + col] = acc[m][n][r];
        }
    }
}

// ---------------------------------------------------------------------------
// Row LayerNorm over 1536 in place; permuted-layout aware. (round-8 verified)
// ---------------------------------------------------------------------------
__global__ __launch_bounds__(256)
void ln_rows(float* __restrict__ X, const float* __restrict__ gam,
             const float* __restrict__ bet)
{
    float* x = X + (long)blockIdx.x * GG;
    const int tid = threadIdx.x;
    float v[6];
    float s = 0.f, q = 0.f;
    #pragma unroll
    for (int i = 0; i < 6; ++i) {
        v[i] = x[tid + i * 256];
        s += v[i]; q += v[i] * v[i];
    }
    #pragma unroll
    for (int o = 32; o; o >>= 1) { s += __shfl_xor(s, o); q += __shfl_xor(q, o); }
    __shared__ float red[2][4];
    const int wave = tid >> 6;
    if ((tid & 63) == 0) { red[0][wave] = s; red[1][wave] = q; }
    __syncthreads();
    float S = 0.f, Q = 0.f;
    #pragma unroll
    for (int w = 0; w < 4; ++w) { S += red[0][w]; Q += red[1][w]; }
    const float mean = S * (1.0f / GG);
    const float var  = Q * (1.0f / GG) - mean * mean;
    const float rs   = rsqrtf(var + LN_EPS);
    #pragma unroll
    for (int i = 0; i < 6; ++i) {
        const int col = tid + i * 256;
        const int c = col & 15, qq = col >> 4;
        const int orig = (qq & 3) * HH + (qq >> 2) * 16 + c;
        x[col] = (v[i] - mean) * rs * gam[orig] + bet[orig];
    }
}

// ---------------------------------------------------------------------------
// Row-partitioned LSTM scan v2: 16 blocks x 16 rows x 768 thr (12 waves).
// Wave w owns hidden blocks {2w, 2w+1} (8 col-frags, all 4 gates in-lane).
// Weights streamed from wave-tiled whT3t with depth-4 register prefetch.
// ---------------------------------------------------------------------------
constexpr int HLD = 392;

__global__ __launch_bounds__(768, 3)
void lstm_scan2(const bf16* __restrict__ whT3t,  // tiled [3][96][12][512]
                const float* __restrict__ xg,    // [T*B][1536(perm)], LN'd
                const float* __restrict__ bias_l,
                const float* __restrict__ ghw_l,
                const float* __restrict__ ghb_l,
                const float* __restrict__ h0_l,
                const float* __restrict__ c0_l,
                float* __restrict__ xout,
                float* __restrict__ hn, float* __restrict__ cn)
{
    __shared__ bf16 hlds[3][16 * HLD];
    __shared__ float part[12][16][2];
    __shared__ float stats[16][2];

    const int tid = threadIdx.x;
    const int w = tid >> 6;               // 0..11
    const int lane = tid & 63;
    const int cc = lane & 15, g = lane >> 4;
    const int b0 = blockIdx.x * 16;
    constexpr size_t PL = (size_t)96 * 12 * 512;   // plane stride (elems)
    const int eo = cc * 32 + g * 8;       // per-lane elem offset within 1KB tile

    for (int i = tid; i < 16 * HH; i += 768) {
        const int row = i / HH, j = i - row * HH;
        bf16 hh, hm, hl;
        split3(h0_l[(size_t)(b0 + row) * HH + j], hh, hm, hl);
        hlds[0][row * HLD + j] = hh;
        hlds[1][row * HLD + j] = hm;
        hlds[2][row * HLD + j] = hl;
    }
    float cst[2][4], gw[2][4], gc[2][4];
    #pragma unroll
    for (int hb = 0; hb < 2; ++hb) {
        const int j = (2 * w + hb) * 16 + cc;
        #pragma unroll
        for (int r = 0; r < 4; ++r)
            cst[hb][r] = c0_l[(size_t)(b0 + g * 4 + r) * HH + j];
        #pragma unroll
        for (int p = 0; p < 4; ++p) {
            const int col = p * HH + j;
            gw[hb][p] = ghw_l[col];
            gc[hb][p] = ghb_l[col] + bias_l[col];
        }
    }
    __syncthreads();

    const f32x4 zero = {0.f, 0.f, 0.f, 0.f};
    for (int t = 0; t < TT; ++t) {
        f32x4 acc[8];
        #pragma unroll
        for (int cf = 0; cf < 8; ++cf) acc[cf] = zero;

        bf16x8 bh[4], bm[4], bl[4];
        // prologue: prefetch n = 0..3  (ks = 0, cf = n)
        #pragma unroll
        for (int n0 = 0; n0 < 4; ++n0) {
            const size_t tb = ((size_t)(8 * w + n0) * 12 + 0) * 512 + eo;
            bh[n0] = *(const bf16x8*)(whT3t + tb);
            bm[n0] = *(const bf16x8*)(whT3t + PL + tb);
            bl[n0] = *(const bf16x8*)(whT3t + 2 * PL + tb);
        }
        bf16x8 a0, a1, a2;
        #pragma unroll
        for (int n = 0; n < 96; ++n) {
            const int ks = n >> 3, cf = n & 7, slot = n & 3;
            if ((n & 7) == 0) {
                const int k = ks * 32 + g * 8;
                a0 = *(const bf16x8*)&hlds[0][cc * HLD + k];
                a1 = *(const bf16x8*)&hlds[1][cc * HLD + k];
                a2 = *(const bf16x8*)&hlds[2][cc * HLD + k];
            }
            f32x4 v = acc[cf];
            v = __builtin_amdgcn_mfma_f32_16x16x32_bf16(a0, bh[slot], v, 0, 0, 0);
            v = __builtin_amdgcn_mfma_f32_16x16x32_bf16(a1, bh[slot], v, 0, 0, 0);
            v = __builtin_amdgcn_mfma_f32_16x16x32_bf16(a2, bh[slot], v, 0, 0, 0);
            v = __builtin_amdgcn_mfma_f32_16x16x32_bf16(a0, bm[slot], v, 0, 0, 0);
            v = __builtin_amdgcn_mfma_f32_16x16x32_bf16(a1, bm[slot], v, 0, 0, 0);
            v = __builtin_amdgcn_mfma_f32_16x16x32_bf16(a0, bl[slot], v, 0, 0, 0);
            acc[cf] = v;
            if (n + 4 < 96) {
                const int n2 = n + 4;
                const size_t tb = ((size_t)(8 * w + (n2 & 7)) * 12 + (n2 >> 3)) * 512 + eo;
                bh[slot] = *(const bf16x8*)(whT3t + tb);
                bm[slot] = *(const bf16x8*)(whT3t + PL + tb);
                bl[slot] = *(const bf16x8*)(whT3t + 2 * PL + tb);
            }
        }
        // ---- LN partials over this wave's 128 cols
        {
            float s[4], q[4];
            #pragma unroll
            for (int r = 0; r < 4; ++r) { s[r] = 0.f; q[r] = 0.f; }
            #pragma unroll
            for (int cf = 0; cf < 8; ++cf)
                #pragma unroll
                for (int r = 0; r < 4; ++r) {
                    const float v = acc[cf][r];
                    s[r] += v; q[r] += v * v;
                }
            #pragma unroll
            for (int r = 0; r < 4; ++r) {
                s[r] += __shfl_xor(s[r], 1); s[r] += __shfl_xor(s[r], 2);
                s[r] += __shfl_xor(s[r], 4); s[r] += __shfl_xor(s[r], 8);
                q[r] += __shfl_xor(q[r], 1); q[r] += __shfl_xor(q[r], 2);
                q[r] += __shfl_xor(q[r], 4); q[r] += __shfl_xor(q[r], 8);
            }
            if (cc == 0) {
                #pragma unroll
                for (int r = 0; r < 4; ++r) {
                    part[w][g * 4 + r][0] = s[r];
                    part[w][g * 4 + r][1] = q[r];
                }
            }
        }
        __syncthreads();
        if (tid < 16) {
            float S = 0.f, Q = 0.f;
            #pragma unroll
            for (int ww = 0; ww < 12; ++ww) { S += part[ww][tid][0]; Q += part[ww][tid][1]; }
            const float mean = S * (1.0f / GG);
            const float var  = Q * (1.0f / GG) - mean * mean;
            stats[tid][0] = mean;
            stats[tid][1] = rsqrtf(var + LN_EPS);
        }
        __syncthreads();
        // ---- cell (all 4 gates of hidden j in-lane)
        const float* xgt = xg + (size_t)t * BB * GG;
        #pragma unroll
        for (int hb = 0; hb < 2; ++hb) {
            const int j = (2 * w + hb) * 16 + cc;
            #pragma unroll
            for (int r = 0; r < 4; ++r) {
                const int row = g * 4 + r;
                const float mean = stats[row][0], rs = stats[row][1];
                float gate[4];
                #pragma unroll
                for (int p = 0; p < 4; ++p) {
                    const int np = (8 * w + 4 * hb + p) * 16 + cc;
                    gate[p] = (acc[4 * hb + p][r] - mean) * rs * gw[hb][p] + gc[hb][p]
                              + xgt[(size_t)(b0 + row) * GG + np];
                }
                const float cnew = sigm(gate[1]) * cst[hb][r] + sigm(gate[0]) * tanhf(gate[3]);
                const float h    = sigm(gate[2]) * tanhf(cnew);
                cst[hb][r] = cnew;
                bf16 hh, hm, hl; split3(h, hh, hm, hl);
                hlds[0][row * HLD + j] = hh;
                hlds[1][row * HLD + j] = hm;
                hlds[2][row * HLD + j] = hl;
                xout[((size_t)t * BB + b0 + row) * HH + j] = h;
                if (t == TT - 1) {
                    hn[(size_t)(b0 + row) * HH + j] = h;
                    cn[(size_t)(b0 + row) * HH + j] = cnew;
                }
            }
        }
        __syncthreads();
    }
}

// ---------------------------------------------------------------------------
extern "C" void kernel_launch(void* const* d_in, const int* in_sizes, int n_in,
                              void* d_out, int out_size, void* d_ws, size_t ws_size,
                              hipStream_t stream)
{
    const float* ent  = (const float*)d_in[0];
    const float* spa  = (const float*)d_in[1];
    const float* sca  = (const float*)d_in[2];
    const float* h0   = (const float*)d_in[3];
    const float* c0   = (const float*)d_in[4];
    const float* wx[3] = { (const float*)d_in[5], (const float*)d_in[6], (const float*)d_in[7] };
    const float* wh   = (const float*)d_in[8];
    const float* bias = (const float*)d_in[9];
    const float* gxw  = (const float*)d_in[10];
    const float* gxb  = (const float*)d_in[11];
    const float* ghw  = (const float*)d_in[12];
    const float* ghb  = (const float*)d_in[13];

    float* out    = (float*)d_out;
    float* out_x  = out;
    float* out_hn = out + (long)TT * BB * HH;
    float* out_cn = out_hn + 3L * BB * HH;

    char* w = (char*)d_ws;
    float* xg    = (float*)w;  w += (size_t)TT * BB * GG * 4;      // 50.3 MB
    bf16*  wxT3  = (bf16*)w;   w += (size_t)3 * GG * 1152 * 2;     // 10.6 MB
    bf16*  whT3t = (bf16*)w;   w += (size_t)3 * 96 * 12 * 512 * 2; // 3.5 MB (tiled)
    float* xf    = (float*)w;  w += (size_t)TT * BB * HH * 4;      // 12.6 MB

    const int M = TT * BB;  // 8192
    for (int l = 0; l < 3; ++l) {
        const int K = (l == 0) ? 1152 : HH;
        transpose_cvt3<<<dim3(GG / 32, K / 32), 256, 0, stream>>>(wx[l], wxT3, K, GG);
        transpose_cvt3_tiled<<<dim3(GG / 32, HH / 32), 256, 0, stream>>>(wh + (long)l * HH * GG, whT3t);

        dim3 pgrid(GG / 128, M / 128);
        if (l == 0)
            gemm_proj<true ><<<pgrid, 256, 0, stream>>>(nullptr, ent, spa, sca, wxT3, xg, K, GG);
        else
            gemm_proj<false><<<pgrid, 256, 0, stream>>>(xf, nullptr, nullptr, nullptr, wxT3, xg, K, GG);
        ln_rows<<<M, 256, 0, stream>>>(xg, gxw + l * GG, gxb + l * GG);

        lstm_scan2<<<16, 768, 0, stream>>>(whT3t, xg,
            bias + l * GG, ghw + l * GG, ghb + l * GG,
            h0 + (long)l * BB * HH, c0 + (long)l * BB * HH,
            (l == 2) ? out_x : xf,
            out_hn + (long)l * BB * HH, out_cn + (long)l * BB * HH);
    }
    (void)in_sizes; (void)n_in; (void)out_size; (void)ws_size;
}

// Round 10
// 8554.961 us; speedup vs baseline: 1.2036x; 1.2036x over previous
//
#include <hip/hip_runtime.h>
#include <math.h>

typedef __bf16 bf16;
typedef __attribute__((ext_vector_type(8))) __bf16 bf16x8;
typedef __attribute__((ext_vector_type(4))) float f32x4;

constexpr int TT = 32, BB = 256, HH = 384, GG = 1536;
constexpr float LN_EPS = 1e-5f;

__device__ __forceinline__ float sigm(float x) { return 1.0f / (1.0f + __expf(-x)); }

// split fp32 into 2 bf16 planes: x = h + l + O(2^-17 x)
__device__ __forceinline__ void split2(float x, bf16& h, bf16& l) {
    h = (bf16)x; l = (bf16)(x - (float)h);
}

// ---------------------------------------------------------------------------
// transpose + fp32 -> 2 bf16 planes, row-major permuted output (for wx):
// in[K][N] -> out[plane][n'][K], n' = ((r>>4)*4+p)*16+(r&15), n = p*384+r.
// ---------------------------------------------------------------------------
__global__ __launch_bounds__(256)
void transpose_cvt2(const float* __restrict__ in, bf16* __restrict__ out,
                    int K, int N)
{
    __shared__ float tile[32][33];
    const int k0 = blockIdx.y * 32;
    const int n0 = blockIdx.x * 32;
    const int tx = threadIdx.x & 31;
    const int ty = threadIdx.x >> 5;
    const size_t PS = (size_t)N * K;
    #pragma unroll
    for (int i = 0; i < 4; ++i)
        tile[ty + i * 8][tx] = in[(long)(k0 + ty + i * 8) * N + n0 + tx];
    __syncthreads();
    #pragma unroll
    for (int i = 0; i < 4; ++i) {
        const int n = n0 + ty + i * 8;
        const int p = n / HH, r = n - p * HH;
        const int orow = ((r >> 4) * 4 + p) * 16 + (r & 15);
        bf16 h, l;
        split2(tile[tx][ty + i * 8], h, l);
        const size_t base = (size_t)orow * K + k0 + tx;
        out[base] = h; out[PS + base] = l;
    }
}

// ---------------------------------------------------------------------------
// transpose + 2-plane split for wh -> WAVE-TILED layout (for the scan):
// elem addr = (pl*96*12 + q*12 + ks)*512 + cc*32 + kk ; orow = q*16+cc,
// k = ks*32+kk. Each 1KB tile is one wave's coalesced B-fragment load.
// (layout verified by round-9 pass)
// ---------------------------------------------------------------------------
__global__ __launch_bounds__(256)
void transpose_cvt2_tiled(const float* __restrict__ in, bf16* __restrict__ out)
{
    __shared__ float tile[32][33];
    const int k0 = blockIdx.y * 32;
    const int n0 = blockIdx.x * 32;
    const int tx = threadIdx.x & 31;
    const int ty = threadIdx.x >> 5;
    constexpr size_t PS = (size_t)96 * 12 * 512;  // elems per plane
    #pragma unroll
    for (int i = 0; i < 4; ++i)
        tile[ty + i * 8][tx] = in[(long)(k0 + ty + i * 8) * GG + n0 + tx];
    __syncthreads();
    #pragma unroll
    for (int i = 0; i < 4; ++i) {
        const int n = n0 + ty + i * 8;
        const int p = n / HH, r = n - p * HH;
        const int orow = ((r >> 4) * 4 + p) * 16 + (r & 15);
        const int q = orow >> 4, cc = orow & 15;
        const int k = k0 + tx;
        const int ks = k >> 5, kk = k & 31;
        bf16 h, l;
        split2(tile[tx][ty + i * 8], h, l);
        const size_t base = ((size_t)q * 12 + ks) * 512 + cc * 32 + kk;
        out[base] = h; out[PS + base] = l;
    }
}

// ---------------------------------------------------------------------------
// 2-plane 3-term MFMA GEMM (projections): C = A @ Bt^T, fp32 in/out.
// Error ~2^-17 relative. 128x128 tile, BK=32, 256 thr.
// ---------------------------------------------------------------------------
template<bool CONCAT>
__global__ __launch_bounds__(256)
void gemm_proj(const float* __restrict__ A,
               const float* __restrict__ Aent, const float* __restrict__ Aspa,
               const float* __restrict__ Asca,
               const bf16* __restrict__ Bt2, float* __restrict__ C,
               int K, int N)
{
    constexpr int LDA = 40;
    __shared__ bf16 As[2][128 * LDA];
    __shared__ bf16 Bs[2][128 * LDA];
    const int tid = threadIdx.x;
    const long bm = (long)blockIdx.y * 128;
    const int bn = blockIdx.x * 128;
    const int srow = tid & 127;
    const int soff = (tid >> 7) * 16;
    const int lane = tid & 63;
    const int wid  = tid >> 6;
    const int wm = (wid >> 1) * 64, wn = (wid & 1) * 64;
    const int cc = lane & 15, g = lane >> 4;
    const size_t PS = (size_t)N * K;

    const f32x4 zero = {0.f, 0.f, 0.f, 0.f};
    f32x4 acc[4][4];
    #pragma unroll
    for (int m = 0; m < 4; ++m)
        #pragma unroll
        for (int n = 0; n < 4; ++n) acc[m][n] = zero;

    for (int k0 = 0; k0 < K; k0 += 32) {
        float va[16];
        if (!CONCAT) {
            const float* p = A + (bm + srow) * (long)K + k0 + soff;
            #pragma unroll
            for (int i = 0; i < 4; ++i) {
                const float4 v = *(const float4*)(p + i * 4);
                va[i*4+0] = v.x; va[i*4+1] = v.y; va[i*4+2] = v.z; va[i*4+3] = v.w;
            }
        } else {
            const int acol = k0 + soff;  // multiple of 16; segment boundaries ok
            const float* p;
            if (acol < 256)      p = Aent + (bm + srow) * 256 + acol;
            else if (acol < 512) p = Aspa + (bm + srow) * 256 + (acol - 256);
            else                 p = Asca + (bm + srow) * 640 + (acol - 512);
            #pragma unroll
            for (int i = 0; i < 4; ++i) {
                const float4 v = *(const float4*)(p + i * 4);
                va[i*4+0] = v.x; va[i*4+1] = v.y; va[i*4+2] = v.z; va[i*4+3] = v.w;
            }
        }
        bf16 ah[16], al[16];
        #pragma unroll
        for (int e = 0; e < 16; ++e) split2(va[e], ah[e], al[e]);
        const bf16* bp = Bt2 + (bn + srow) * (long)K + k0 + soff;
        const bf16x8 b00 = *(const bf16x8*)bp;
        const bf16x8 b01 = *(const bf16x8*)(bp + 8);
        const bf16x8 b10 = *(const bf16x8*)(bp + PS);
        const bf16x8 b11 = *(const bf16x8*)(bp + PS + 8);
        __syncthreads();
        *(bf16x8*)&As[0][srow * LDA + soff]     = *(bf16x8*)&ah[0];
        *(bf16x8*)&As[0][srow * LDA + soff + 8] = *(bf16x8*)&ah[8];
        *(bf16x8*)&As[1][srow * LDA + soff]     = *(bf16x8*)&al[0];
        *(bf16x8*)&As[1][srow * LDA + soff + 8] = *(bf16x8*)&al[8];
        *(bf16x8*)&Bs[0][srow * LDA + soff]     = b00;
        *(bf16x8*)&Bs[0][srow * LDA + soff + 8] = b01;
        *(bf16x8*)&Bs[1][srow * LDA + soff]     = b10;
        *(bf16x8*)&Bs[1][srow * LDA + soff + 8] = b11;
        __syncthreads();
        bf16x8 a0[4], a1[4], bb[4];
        #pragma unroll
        for (int m = 0; m < 4; ++m) {
            const int off = (wm + m * 16 + cc) * LDA + g * 8;
            a0[m] = *(const bf16x8*)&As[0][off];
            a1[m] = *(const bf16x8*)&As[1][off];
        }
        // B hi: a_hi*b_hi + a_lo*b_hi
        #pragma unroll
        for (int n = 0; n < 4; ++n)
            bb[n] = *(const bf16x8*)&Bs[0][(wn + n * 16 + cc) * LDA + g * 8];
        #pragma unroll
        for (int m = 0; m < 4; ++m)
            #pragma unroll
            for (int n = 0; n < 4; ++n) {
                acc[m][n] = __builtin_amdgcn_mfma_f32_16x16x32_bf16(a0[m], bb[n], acc[m][n], 0, 0, 0);
                acc[m][n] = __builtin_amdgcn_mfma_f32_16x16x32_bf16(a1[m], bb[n], acc[m][n], 0, 0, 0);
            }
        // B lo: a_hi*b_lo
        #pragma unroll
        for (int n = 0; n < 4; ++n)
            bb[n] = *(const bf16x8*)&Bs[1][(wn + n * 16 + cc) * LDA + g * 8];
        #pragma unroll
        for (int m = 0; m < 4; ++m)
            #pragma unroll
            for (int n = 0; n < 4; ++n)
                acc[m][n] = __builtin_amdgcn_mfma_f32_16x16x32_bf16(a0[m], bb[n], acc[m][n], 0, 0, 0);
    }
    #pragma unroll
    for (int m = 0; m < 4; ++m) {
        const long row0 = bm + wm + m * 16 + g * 4;
        #pragma unroll
        for (int n = 0; n < 4; ++n) {
            const int col = bn + wn + n * 16 + cc;
            #pragma unroll
            for (int r = 0; r < 4; ++r)
                C[(row0 + r) * (long)N + col] = acc[m][n][r];
        }
    }
}

// ---------------------------------------------------------------------------
// Row LayerNorm over 1536 in place; permuted-layout aware. (round-8 verified)
// ---------------------------------------------------------------------------
__global__ __launch_bounds__(256)
void ln_rows(float* __restrict__ X, const float* __restrict__ gam,
             const float* __restrict__ bet)
{
    float* x = X + (long)blockIdx.x * GG;
    const int tid = threadIdx.x;
    float v[6];
    float s = 0.f, q = 0.f;
    #pragma unroll
    for (int i = 0; i < 6; ++i) {
        v[i] = x[tid + i * 256];
        s += v[i]; q += v[i] * v[i];
    }
    #pragma unroll
    for (int o = 32; o; o >>= 1) { s += __shfl_xor(s, o); q += __shfl_xor(q, o); }
    __shared__ float red[2][4];
    const int wave = tid >> 6;
    if ((tid & 63) == 0) { red[0][wave] = s; red[1][wave] = q; }
    __syncthreads();
    float S = 0.f, Q = 0.f;
    #pragma unroll
    for (int w = 0; w < 4; ++w) { S += red[0][w]; Q += red[1][w]; }
    const float mean = S * (1.0f / GG);
    const float var  = Q * (1.0f / GG) - mean * mean;
    const float rs   = rsqrtf(var + LN_EPS);
    #pragma unroll
    for (int i = 0; i < 6; ++i) {
        const int col = tid + i * 256;
        const int c = col & 15, qq = col >> 4;
        const int orig = (qq & 3) * HH + (qq >> 2) * 16 + c;
        x[col] = (v[i] - mean) * rs * gam[orig] + bet[orig];
    }
}

// ---------------------------------------------------------------------------
// LSTM scan v3: 8 blocks x 32 rows x 768 thr (12 waves) — 1 block per XCD,
// 2-plane weights (2.33 MB) stay L2-resident. Wave w owns hidden blocks
// {2w,2w+1}; 2 row-fragments; depth-4 tile prefetch from wave-tiled whT2t.
// ---------------------------------------------------------------------------
constexpr int HLD = 392;

__global__ __launch_bounds__(768, 3)
void lstm_scan3(const bf16* __restrict__ whT2t,  // tiled [2][96][12][512]
                const float* __restrict__ xg,    // [T*B][1536(perm)], LN'd
                const float* __restrict__ bias_l,
                const float* __restrict__ ghw_l,
                const float* __restrict__ ghb_l,
                const float* __restrict__ h0_l,
                const float* __restrict__ c0_l,
                float* __restrict__ xout,
                float* __restrict__ hn, float* __restrict__ cn)
{
    __shared__ bf16 hlds[2][32 * HLD];   // 49 KB h planes
    __shared__ float part[12][32][2];    // 3 KB
    __shared__ float stats[32][2];

    const int tid = threadIdx.x;
    const int w = tid >> 6;              // 0..11
    const int lane = tid & 63;
    const int cc = lane & 15, g = lane >> 4;
    const int b0 = blockIdx.x * 32;      // batch rows [b0, b0+32)
    constexpr size_t PL = (size_t)96 * 12 * 512;   // plane stride (elems)
    const int eo = cc * 32 + g * 8;      // lane offset within 1KB tile

    for (int i = tid; i < 32 * HH; i += 768) {
        const int row = i / HH, j = i - row * HH;
        bf16 hh, hl;
        split2(h0_l[(size_t)(b0 + row) * HH + j], hh, hl);
        hlds[0][row * HLD + j] = hh;
        hlds[1][row * HLD + j] = hl;
    }
    float cst[2][2][4], gw[2][4], gc[2][4];
    #pragma unroll
    for (int hb = 0; hb < 2; ++hb) {
        const int j = (2 * w + hb) * 16 + cc;
        #pragma unroll
        for (int rf = 0; rf < 2; ++rf)
            #pragma unroll
            for (int r = 0; r < 4; ++r)
                cst[hb][rf][r] = c0_l[(size_t)(b0 + rf * 16 + g * 4 + r) * HH + j];
        #pragma unroll
        for (int p = 0; p < 4; ++p) {
            const int col = p * HH + j;
            gw[hb][p] = ghw_l[col];
            gc[hb][p] = ghb_l[col] + bias_l[col];
        }
    }
    __syncthreads();

    const f32x4 zero = {0.f, 0.f, 0.f, 0.f};
    for (int t = 0; t < TT; ++t) {
        f32x4 acc[8][2];
        #pragma unroll
        for (int cf = 0; cf < 8; ++cf) {
            acc[cf][0] = zero; acc[cf][1] = zero;
        }
        bf16x8 bh[4], bl[4];
        #pragma unroll
        for (int n0 = 0; n0 < 4; ++n0) {
            const size_t tb = ((size_t)(8 * w + n0) * 12 + 0) * 512 + eo;
            bh[n0] = *(const bf16x8*)(whT2t + tb);
            bl[n0] = *(const bf16x8*)(whT2t + PL + tb);
        }
        bf16x8 a0[2], a1[2];
        #pragma unroll
        for (int n = 0; n < 96; ++n) {
            const int ks = n >> 3, cf = n & 7, slot = n & 3;
            if (cf == 0) {
                const int k = ks * 32 + g * 8;
                a0[0] = *(const bf16x8*)&hlds[0][cc * HLD + k];
                a1[0] = *(const bf16x8*)&hlds[1][cc * HLD + k];
                a0[1] = *(const bf16x8*)&hlds[0][(16 + cc) * HLD + k];
                a1[1] = *(const bf16x8*)&hlds[1][(16 + cc) * HLD + k];
            }
            #pragma unroll
            for (int rf = 0; rf < 2; ++rf) {
                f32x4 v = acc[cf][rf];
                v = __builtin_amdgcn_mfma_f32_16x16x32_bf16(a0[rf], bh[slot], v, 0, 0, 0);
                v = __builtin_amdgcn_mfma_f32_16x16x32_bf16(a1[rf], bh[slot], v, 0, 0, 0);
                v = __builtin_amdgcn_mfma_f32_16x16x32_bf16(a0[rf], bl[slot], v, 0, 0, 0);
                acc[cf][rf] = v;
            }
            if (n + 4 < 96) {
                const int n2 = n + 4;
                const size_t tb = ((size_t)(8 * w + (n2 & 7)) * 12 + (n2 >> 3)) * 512 + eo;
                bh[slot] = *(const bf16x8*)(whT2t + tb);
                bl[slot] = *(const bf16x8*)(whT2t + PL + tb);
            }
        }
        // ---- LN partials: this wave's 128 cols for its 32 rows
        {
            float s[2][4], q[2][4];
            #pragma unroll
            for (int rf = 0; rf < 2; ++rf)
                #pragma unroll
                for (int r = 0; r < 4; ++r) { s[rf][r] = 0.f; q[rf][r] = 0.f; }
            #pragma unroll
            for (int cf = 0; cf < 8; ++cf)
                #pragma unroll
                for (int rf = 0; rf < 2; ++rf)
                    #pragma unroll
                    for (int r = 0; r < 4; ++r) {
                        const float v = acc[cf][rf][r];
                        s[rf][r] += v; q[rf][r] += v * v;
                    }
            #pragma unroll
            for (int rf = 0; rf < 2; ++rf)
                #pragma unroll
                for (int r = 0; r < 4; ++r) {
                    float sv = s[rf][r], qv = q[rf][r];
                    sv += __shfl_xor(sv, 1); sv += __shfl_xor(sv, 2);
                    sv += __shfl_xor(sv, 4); sv += __shfl_xor(sv, 8);
                    qv += __shfl_xor(qv, 1); qv += __shfl_xor(qv, 2);
                    qv += __shfl_xor(qv, 4); qv += __shfl_xor(qv, 8);
                    if (cc == 0) {
                        part[w][rf * 16 + g * 4 + r][0] = sv;
                        part[w][rf * 16 + g * 4 + r][1] = qv;
                    }
                }
        }
        __syncthreads();
        if (tid < 32) {
            float S = 0.f, Q = 0.f;
            #pragma unroll
            for (int ww = 0; ww < 12; ++ww) { S += part[ww][tid][0]; Q += part[ww][tid][1]; }
            const float mean = S * (1.0f / GG);
            const float var  = Q * (1.0f / GG) - mean * mean;
            stats[tid][0] = mean;
            stats[tid][1] = rsqrtf(var + LN_EPS);
        }
        __syncthreads();
        // ---- cell: all 4 gates of hidden j in-lane
        const float* xgt = xg + (size_t)t * BB * GG;
        #pragma unroll
        for (int hb = 0; hb < 2; ++hb) {
            const int j = (2 * w + hb) * 16 + cc;
            #pragma unroll
            for (int rf = 0; rf < 2; ++rf) {
                #pragma unroll
                for (int r = 0; r < 4; ++r) {
                    const int row = rf * 16 + g * 4 + r;
                    const float mean = stats[row][0], rs = stats[row][1];
                    float gate[4];
                    #pragma unroll
                    for (int p = 0; p < 4; ++p) {
                        const int np = (8 * w + 4 * hb + p) * 16 + cc;
                        gate[p] = (acc[4 * hb + p][rf][r] - mean) * rs * gw[hb][p] + gc[hb][p]
                                  + xgt[(size_t)(b0 + row) * GG + np];
                    }
                    const float cnew = sigm(gate[1]) * cst[hb][rf][r] + sigm(gate[0]) * tanhf(gate[3]);
                    const float h    = sigm(gate[2]) * tanhf(cnew);
                    cst[hb][rf][r] = cnew;
                    bf16 hh, hl; split2(h, hh, hl);
                    hlds[0][row * HLD + j] = hh;
                    hlds[1][row * HLD + j] = hl;
                    xout[((size_t)t * BB + b0 + row) * HH + j] = h;
                    if (t == TT - 1) {
                        hn[(size_t)(b0 + row) * HH + j] = h;
                        cn[(size_t)(b0 + row) * HH + j] = cnew;
                    }
                }
            }
        }
        __syncthreads();
    }
}

// ---------------------------------------------------------------------------
extern "C" void kernel_launch(void* const* d_in, const int* in_sizes, int n_in,
                              void* d_out, int out_size, void* d_ws, size_t ws_size,
                              hipStream_t stream)
{
    const float* ent  = (const float*)d_in[0];
    const float* spa  = (const float*)d_in[1];
    const float* sca  = (const float*)d_in[2];
    const float* h0   = (const float*)d_in[3];
    const float* c0   = (const float*)d_in[4];
    const float* wx[3] = { (const float*)d_in[5], (const float*)d_in[6], (const float*)d_in[7] };
    const float* wh   = (const float*)d_in[8];
    const float* bias = (const float*)d_in[9];
    const float* gxw  = (const float*)d_in[10];
    const float* gxb  = (const float*)d_in[11];
    const float* ghw  = (const float*)d_in[12];
    const float* ghb  = (const float*)d_in[13];

    float* out    = (float*)d_out;
    float* out_x  = out;
    float* out_hn = out + (long)TT * BB * HH;
    float* out_cn = out_hn + 3L * BB * HH;

    char* w = (char*)d_ws;
    float* xg    = (float*)w;  w += (size_t)TT * BB * GG * 4;      // 50.3 MB
    bf16*  wxT2  = (bf16*)w;   w += (size_t)2 * GG * 1152 * 2;     // 7.1 MB
    bf16*  whT2t = (bf16*)w;   w += (size_t)2 * 96 * 12 * 512 * 2; // 2.36 MB (tiled)
    float* xf    = (float*)w;  w += (size_t)TT * BB * HH * 4;      // 12.6 MB

    const int M = TT * BB;  // 8192
    for (int l = 0; l < 3; ++l) {
        const int K = (l == 0) ? 1152 : HH;
        transpose_cvt2<<<dim3(GG / 32, K / 32), 256, 0, stream>>>(wx[l], wxT2, K, GG);
        transpose_cvt2_tiled<<<dim3(GG / 32, HH / 32), 256, 0, stream>>>(wh + (long)l * HH * GG, whT2t);

        dim3 pgrid(GG / 128, M / 128);
        if (l == 0)
            gemm_proj<true ><<<pgrid, 256, 0, stream>>>(nullptr, ent, spa, sca, wxT2, xg, K, GG);
        else
            gemm_proj<false><<<pgrid, 256, 0, stream>>>(xf, nullptr, nullptr, nullptr, wxT2, xg, K, GG);
        ln_rows<<<M, 256, 0, stream>>>(xg, gxw + l * GG, gxb + l * GG);

        lstm_scan3<<<8, 768, 0, stream>>>(whT2t, xg,
            bias + l * GG, ghw + l * GG, ghb + l * GG,
            h0 + (long)l * BB * HH, c0 + (long)l * BB * HH,
            (l == 2) ? out_x : xf,
            out_hn + (long)l * BB * HH, out_cn + (long)l * BB * HH);
    }
    (void)in_sizes; (void)n_in; (void)out_size; (void)ws_size;
}